// Round 2
// baseline (414.912 us; speedup 1.0000x reference)
//
#include <hip/hip_runtime.h>
#include <hip/hip_bf16.h>

// DecoderLayer cross-attention, MI355X/gfx950. Round 5.
// B=4, Sq=2048, Skv=4096, D=512. fp32 in/out, bf16 MFMA internally.
// R5 changes vs R4 (post-mortem of the 260us regression):
//  - attn: BACK to BM=64 / 512 blocks / Qs[64][528] (R3 geometry: perfect 1-round pack
//          at 2 blocks/CU, 1x K/V L2 streaming, mod-8 dword stride = low bank conflict),
//          but now 512 THREADS / 8 waves: per-wave acc halves to oacc[2][8]=64 regs ->
//          __launch_bounds__(512,4) -> 4 waves/SIMD (2x R3 occupancy), same block count.
//  - attn: setprio removed (R4 confounder; m190 precedent on lockstep structures).
//  - cvt merged kernel kept (benign).
// ws layout (phase-overlapped), unchanged:
//   Qb  bf16 [8192][512]      @ 0           (8,388,608)
//   Kb  bf16 [16384][512]     @ 8,388,608   (16,777,216)
//   Vt  bf16 [4][512][4096]   @ 25,165,824  (16,777,216)
//   region B @ 41,943,040:
//     phase1 (pre-proj): xb 8.4M | encb @+8.4M 16.8M | wqb/wkb/wvb @+25.2M 0.5M each
//     phase2 (attn):     Op f32 [NSPLIT][8192][512] | lp f32 [NSPLIT][8192]
//   need(NSPLIT=4) = 109,182,976 B ; need(NSPLIT=2) = 75,563,008 B (known available)

typedef __bf16 bf16;
typedef __attribute__((ext_vector_type(8))) __bf16 bf16x8;
typedef __attribute__((ext_vector_type(4))) float f32x4;

#define DM 512

// ---------------- fp32 -> bf16 convert prepass (single launch, 5 regions) -----------------
__global__ __launch_bounds__(256) void cvt_all_kernel(
    const float* __restrict__ x,   bf16* __restrict__ xb,
    const float* __restrict__ enc, bf16* __restrict__ encb,
    const float* __restrict__ wq,  bf16* __restrict__ wqb,
    const float* __restrict__ wk,  bf16* __restrict__ wkb,
    const float* __restrict__ wv,  bf16* __restrict__ wvb)
{
    int g = blockIdx.x * 256 + threadIdx.x;
    const float* src; bf16* dst;
    if (g < 524288)       { src = x;   dst = xb; }
    else if (g < 1572864) { g -= 524288;  src = enc; dst = encb; }
    else if (g < 1605632) { g -= 1572864; src = wq;  dst = wqb; }
    else if (g < 1638400) { g -= 1605632; src = wk;  dst = wkb; }
    else                  { g -= 1638400; src = wv;  dst = wvb; }
    const float4 f0 = *reinterpret_cast<const float4*>(src + (size_t)g * 8);
    const float4 f1 = *reinterpret_cast<const float4*>(src + (size_t)g * 8 + 4);
    bf16x8 v;
    v[0]=(bf16)f0.x; v[1]=(bf16)f0.y; v[2]=(bf16)f0.z; v[3]=(bf16)f0.w;
    v[4]=(bf16)f1.x; v[5]=(bf16)f1.y; v[6]=(bf16)f1.z; v[7]=(bf16)f1.w;
    *reinterpret_cast<bf16x8*>(dst + (size_t)g * 8) = v;
}

// ---------------- Projection GEMMs (bf16 in): out = A @ W^T + b, stored bf16 ---------------
// KV=false: Q row-major. KV=true: K row-major + V transposed Vt[b][e][t].
template<bool KV>
__global__ __launch_bounds__(256) void proj_kernel(const bf16* __restrict__ A,
    const bf16* __restrict__ W0, const float* __restrict__ b0, bf16* __restrict__ out0,
    const bf16* __restrict__ W1, const float* __restrict__ b1, bf16* __restrict__ out1)
{
    __shared__ __align__(16) bf16 As[2][64][40];
    __shared__ __align__(16) bf16 W0s[2][64][40];
    __shared__ __align__(16) bf16 W1s[2][64][40];

    const int tid  = threadIdx.x;
    const int w    = tid >> 6, lane = tid & 63, quad = lane >> 4, l15 = lane & 15;
    const int wr   = w >> 1, wc = w & 1;
    const int n0   = blockIdx.x * 64;
    const int m0   = blockIdx.y * 64;
    const int srow = tid >> 2;
    const int scol = (tid & 3) * 8;

    f32x4 acc0[2][2] = {}, acc1[2][2] = {};
    bf16x8 ra, rw0, rw1;

    auto prefetch = [&](int kk) {
        ra  = *reinterpret_cast<const bf16x8*>(A  + (size_t)(m0 + srow) * DM + kk + scol);
        rw0 = *reinterpret_cast<const bf16x8*>(W0 + (size_t)(n0 + srow) * DM + kk + scol);
        if constexpr (KV)
            rw1 = *reinterpret_cast<const bf16x8*>(W1 + (size_t)(n0 + srow) * DM + kk + scol);
    };
    auto store_lds = [&](int p) {
        *reinterpret_cast<bf16x8*>(&As[p][srow][scol])  = ra;
        *reinterpret_cast<bf16x8*>(&W0s[p][srow][scol]) = rw0;
        if constexpr (KV)
            *reinterpret_cast<bf16x8*>(&W1s[p][srow][scol]) = rw1;
    };

    prefetch(0);
    store_lds(0);
    __syncthreads();

    for (int step = 0; step < 16; step++) {
        const int p = step & 1;
        if (step < 15) prefetch((step + 1) * 32);

        bf16x8 af[2], bf0[2], bf1[2];
#pragma unroll
        for (int mt = 0; mt < 2; mt++)
            af[mt] = *reinterpret_cast<const bf16x8*>(&As[p][32*wr + 16*mt + l15][quad*8]);
#pragma unroll
        for (int nt = 0; nt < 2; nt++)
            bf0[nt] = *reinterpret_cast<const bf16x8*>(&W0s[p][32*wc + 16*nt + l15][quad*8]);
        if constexpr (KV) {
#pragma unroll
            for (int nt = 0; nt < 2; nt++)
                bf1[nt] = *reinterpret_cast<const bf16x8*>(&W1s[p][32*wc + 16*nt + l15][quad*8]);
        }
#pragma unroll
        for (int mt = 0; mt < 2; mt++)
#pragma unroll
            for (int nt = 0; nt < 2; nt++) {
                acc0[mt][nt] = __builtin_amdgcn_mfma_f32_16x16x32_bf16(af[mt], bf0[nt], acc0[mt][nt], 0, 0, 0);
                if constexpr (KV)
                    acc1[mt][nt] = __builtin_amdgcn_mfma_f32_16x16x32_bf16(af[mt], bf1[nt], acc1[mt][nt], 0, 0, 0);
            }

        if (step < 15) store_lds(p ^ 1);
        __syncthreads();
    }

#pragma unroll
    for (int mt = 0; mt < 2; mt++)
#pragma unroll
        for (int nt = 0; nt < 2; nt++) {
            const int coll = 32*wc + 16*nt + l15;
            const int rowl = 32*wr + 16*mt + quad*4;
            {
                const float bv = b0[n0 + coll];
                f32x4 c = acc0[mt][nt];
#pragma unroll
                for (int r = 0; r < 4; r++)
                    out0[(size_t)(m0 + rowl + r) * DM + n0 + coll] = (bf16)(c[r] + bv);
            }
            if constexpr (KV) {
                const float bv = b1[n0 + coll];
                f32x4 c = acc1[mt][nt];
                const int gr = m0 + rowl;
                const int bidx = gr >> 12, t = gr & 4095;
                const int e = n0 + coll;
                union { uint2 u; bf16 h[4]; } pk;
#pragma unroll
                for (int r = 0; r < 4; r++) pk.h[r] = (bf16)(c[r] + bv);
                *reinterpret_cast<uint2*>(out1 + (((size_t)(bidx * 512 + e)) << 12) + t) = pk.u;
            }
        }
}

// ---------------- Fused attention: BM=64, BN=64, 8 waves, no-max online softmax ------------
// 512 threads. wr = w>>2 (q-row half), wc = w&3 (kv-col / D-col group).
// QK: wave (wr,wc) computes S[32wr..+32][16wc..+16]; A from LDS Qs, B (K) from global.
// PV: wave (wr,wc) computes O[32wr..+32][128wc..+128]; A = P from LDS, B = V from global.
// oacc[2][8]=64 regs -> launch_bounds(512,4): 2 blocks/CU, 4 waves/SIMD (2x R3 occupancy).
// Grid 512 blocks = exactly one residency round. 2 barriers/tile.
template<int NSPLIT>
__global__ __launch_bounds__(512, 4) void attn_kernel(const bf16* __restrict__ Qb,
                                                      const bf16* __restrict__ Kb,
                                                      const bf16* __restrict__ Vt,
                                                      float* __restrict__ Op,
                                                      float* __restrict__ lp)
{
    __shared__ __align__(16) bf16 Qs[64][528];   // 67,584 B; 264 dw stride (mod32=8) - measured-good
    __shared__ __align__(16) bf16 Ps[64][80];    // 10,240 B; 40 dw stride
    __shared__ float lred[64];

    const int tid  = threadIdx.x;
    const int w    = tid >> 6, lane = tid & 63, quad = lane >> 4, l15 = lane & 15;
    const int wr   = w >> 2, wc = w & 3;

    // XCD-swizzle: group all q-blocks of one (b,z) combo on one XCD (L2 locality).
    const int id = blockIdx.x;                   // 1D grid, 128*NSPLIT blocks
    const int xcd = id & 7, slot = id >> 3;
    int combo, qblk;
    if (NSPLIT == 4) { combo = xcd * 2 + (slot >> 5); qblk = slot & 31; }
    else             { combo = xcd;                   qblk = slot;      }
    const int b = combo & 3, z = combo >> 2;
    const int q0 = qblk * 64;
    const int KVLEN = 4096 / NSPLIT, NT = KVLEN / 64, tb = z * KVLEN;

    // stage Q tile [64][512] once
    {
        const bf16* src = Qb + (size_t)(b * 2048 + q0) * DM;
#pragma unroll
        for (int i = 0; i < 8; i++) {
            const int G = tid + 512 * i;         // 4096 chunks of 16 B
            const int row = G >> 6, cg = G & 63;
            *reinterpret_cast<bf16x8*>(&Qs[row][cg * 8]) =
                *reinterpret_cast<const bf16x8*>(src + (size_t)row * DM + cg * 8);
        }
    }
    if (tid < 64) lred[tid] = 0.f;
    __syncthreads();

    f32x4 oacc[2][8] = {};
    float lsum[2][4] = {};
    const float kexp = 1.44269504088896f * 0.044194173824159216f;  // log2(e)/sqrt(512)

    const bf16* krow0 = Kb + (size_t)(b * 4096 + tb + 16*wc + l15) * DM + quad * 8;
    const bf16* vrow0 = Vt + ((size_t)(b * 512 + 128*wc + l15) << 12) + tb + quad * 8;

    for (int tt = 0; tt < NT; tt++) {
        f32x4 sacc[2] = {};
        const bf16* krow = krow0 + (size_t)tt * 64 * DM;
#pragma unroll 4
        for (int k4 = 0; k4 < 16; k4++) {
            bf16x8 bfr = *reinterpret_cast<const bf16x8*>(krow + k4 * 32);
#pragma unroll
            for (int mt = 0; mt < 2; mt++) {
                bf16x8 afr = *reinterpret_cast<const bf16x8*>(&Qs[32*wr + 16*mt + l15][k4*32 + quad*8]);
                sacc[mt] = __builtin_amdgcn_mfma_f32_16x16x32_bf16(afr, bfr, sacc[mt], 0, 0, 0);
            }
        }

        // exp, accumulate l, P -> LDS (C-layout -> A-layout)
#pragma unroll
        for (int mt = 0; mt < 2; mt++)
#pragma unroll
            for (int r = 0; r < 4; r++) {
                const float p = exp2f(sacc[mt][r] * kexp);
                lsum[mt][r] += p;
                Ps[32*wr + 16*mt + quad*4 + r][16*wc + l15] = (bf16)p;
            }
        __syncthreads();

        // PV: O[32wr.., 128wc..] += P[32wr..,64] * V[64, 128wc..]
        const bf16* vrow = vrow0 + tt * 64;
#pragma unroll
        for (int ks2 = 0; ks2 < 2; ks2++) {
            bf16x8 ap[2];
#pragma unroll
            for (int mt = 0; mt < 2; mt++)
                ap[mt] = *reinterpret_cast<const bf16x8*>(&Ps[32*wr + 16*mt + l15][ks2*32 + quad*8]);
#pragma unroll
            for (int nt = 0; nt < 8; nt++) {
                bf16x8 vf = *reinterpret_cast<const bf16x8*>(vrow + ((size_t)(16*nt) << 12) + ks2*32);
#pragma unroll
                for (int mt = 0; mt < 2; mt++)
                    oacc[mt][nt] = __builtin_amdgcn_mfma_f32_16x16x32_bf16(ap[mt], vf, oacc[mt][nt], 0, 0, 0);
            }
        }
        __syncthreads();   // protect Ps for next tile
    }

    // l reduction across lanes/waves (4 wc-waves contribute partial sums per row)
#pragma unroll
    for (int mt = 0; mt < 2; mt++)
#pragma unroll
        for (int r = 0; r < 4; r++)
            atomicAdd(&lred[32*wr + 16*mt + quad*4 + r], lsum[mt][r]);
    __syncthreads();

    if (tid < 64) lp[(size_t)z * 8192 + b * 2048 + q0 + tid] = lred[tid];
#pragma unroll
    for (int mt = 0; mt < 2; mt++)
#pragma unroll
        for (int r = 0; r < 4; r++) {
            const int row = 32*wr + 16*mt + quad*4 + r;
            float* obase = Op + ((size_t)z * 8192 + b * 2048 + q0 + row) * DM;
#pragma unroll
            for (int nt = 0; nt < 8; nt++)
                obase[128*wc + 16*nt + l15] = oacc[mt][nt][r];
        }
}

// ---------------- Combine split partials: out = sum_z Op[z] / sum_z l[z] -------------------
template<int NSPLIT>
__global__ __launch_bounds__(256) void reduce_kernel(const float* __restrict__ Op,
                                                     const float* __restrict__ lp,
                                                     float* __restrict__ out)
{
    const int g = blockIdx.x * 256 + threadIdx.x;    // 1,048,576 threads x float4
    const size_t e = (size_t)g * 4;
    const int row = g >> 7;
    float4 o = *reinterpret_cast<const float4*>(Op + e);
    float l = lp[row];
#pragma unroll
    for (int zz = 1; zz < NSPLIT; zz++) {
        float4 a = *reinterpret_cast<const float4*>(Op + (size_t)zz * 4194304 + e);
        o.x += a.x; o.y += a.y; o.z += a.z; o.w += a.w;
        l += lp[zz * 8192 + row];
    }
    const float linv = 1.0f / l;
    o.x *= linv; o.y *= linv; o.z *= linv; o.w *= linv;
    *reinterpret_cast<float4*>(out + e) = o;
}

extern "C" void kernel_launch(void* const* d_in, const int* in_sizes, int n_in,
                              void* d_out, int out_size, void* d_ws, size_t ws_size,
                              hipStream_t stream)
{
    const float* x   = (const float*)d_in[0];
    const float* enc = (const float*)d_in[1];
    const float* wq  = (const float*)d_in[2];
    const float* bq  = (const float*)d_in[3];
    const float* wk  = (const float*)d_in[4];
    const float* bk  = (const float*)d_in[5];
    const float* wv  = (const float*)d_in[6];
    const float* bv  = (const float*)d_in[7];
    float* out = (float*)d_out;

    char* ws = (char*)d_ws;
    bf16*  Qb   = (bf16*)ws;
    bf16*  Kb   = (bf16*)(ws + 8388608);
    bf16*  Vt   = (bf16*)(ws + 25165824);
    bf16*  xb   = (bf16*)(ws + 41943040);
    bf16*  encb = (bf16*)(ws + 50331648);
    bf16*  wqb  = (bf16*)(ws + 67108864);
    bf16*  wkb  = (bf16*)(ws + 67633152);
    bf16*  wvb  = (bf16*)(ws + 68157440);
    float* Op   = (float*)(ws + 41943040);          // overlaps xb/encb/w*b (phase 2)
    // lp placed after Op per NSPLIT below

    // prepass: fp32 -> bf16, single launch
    hipLaunchKernelGGL(cvt_all_kernel, dim3(6528), dim3(256), 0, stream,
                       x, xb, enc, encb, wq, wqb, wk, wkb, wv, wvb);

    // projections
    hipLaunchKernelGGL((proj_kernel<false>), dim3(8, 128), dim3(256), 0, stream,
                       xb, wqb, bq, Qb, (const bf16*)nullptr, (const float*)nullptr, (bf16*)nullptr);
    hipLaunchKernelGGL((proj_kernel<true>),  dim3(8, 256), dim3(256), 0, stream,
                       encb, wkb, bk, Kb, wvb, bv, Vt);

    // attention + combine
    if (ws_size >= 109182976ull) {
        float* lp = (float*)(ws + 41943040 + 4ull * 16777216);
        hipLaunchKernelGGL((attn_kernel<4>), dim3(512), dim3(512), 0, stream, Qb, Kb, Vt, Op, lp);
        hipLaunchKernelGGL((reduce_kernel<4>), dim3(4096), dim3(256), 0, stream, Op, lp, out);
    } else {
        float* lp = (float*)(ws + 41943040 + 2ull * 16777216);
        hipLaunchKernelGGL((attn_kernel<2>), dim3(256), dim3(512), 0, stream, Qb, Kb, Vt, Op, lp);
        hipLaunchKernelGGL((reduce_kernel<2>), dim3(4096), dim3(256), 0, stream, Op, lp, out);
    }
}

// Round 3
// 315.222 us; speedup vs baseline: 1.3163x; 1.3163x over previous
//
#include <hip/hip_runtime.h>
#include <hip/hip_bf16.h>

// DecoderLayer cross-attention, MI355X/gfx950. Round 6.
// B=4, Sq=2048, Skv=4096, D=512. fp32 in/out, bf16 MFMA internally.
// R6 changes vs R5 (post-mortem: R4/R5 prove homogeneous-occupancy moves fail;
// duration tracks per-wave VMEM redundancy, not occupancy):
//  - attn: PRODUCER-CONSUMER wave specialization on the R3 geometry.
//    512 threads: waves 0-3 = QK (stream K, S->exp->Ps), waves 4-7 = PV (stream V, Ps->O).
//    Ps double-buffered -> 1 barrier/tile; QK(t+1) overlaps PV(t). Each SIMD: 1 QK + 1 PV.
//    Per-wave tiles identical to R3 (zero redundant global traffic, MFMA:VMEM 4:1).
//  - NSPLIT=2 always: 256 blocks x 1 block/CU (LDS 88.3KB) = exactly 1 residency round;
//    halves Op partial traffic vs NSPLIT=4.
// ws layout (phase-overlapped):
//   Qb  bf16 [8192][512]      @ 0           (8,388,608)
//   Kb  bf16 [16384][512]     @ 8,388,608   (16,777,216)
//   Vt  bf16 [4][512][4096]   @ 25,165,824  (16,777,216)
//   region B @ 41,943,040:
//     phase1 (pre-proj): xb 8.4M | encb @+8.4M 16.8M | wqb/wkb/wvb @+25.2M 0.5M each
//     phase2 (attn):     Op f32 [2][8192][512] | lp f32 [2][8192]  (need 75,563,008 B)

typedef __bf16 bf16;
typedef __attribute__((ext_vector_type(8))) __bf16 bf16x8;
typedef __attribute__((ext_vector_type(4))) float f32x4;

#define DM 512

// ---------------- fp32 -> bf16 convert prepass (single launch, 5 regions) -----------------
__global__ __launch_bounds__(256) void cvt_all_kernel(
    const float* __restrict__ x,   bf16* __restrict__ xb,
    const float* __restrict__ enc, bf16* __restrict__ encb,
    const float* __restrict__ wq,  bf16* __restrict__ wqb,
    const float* __restrict__ wk,  bf16* __restrict__ wkb,
    const float* __restrict__ wv,  bf16* __restrict__ wvb)
{
    int g = blockIdx.x * 256 + threadIdx.x;
    const float* src; bf16* dst;
    if (g < 524288)       { src = x;   dst = xb; }
    else if (g < 1572864) { g -= 524288;  src = enc; dst = encb; }
    else if (g < 1605632) { g -= 1572864; src = wq;  dst = wqb; }
    else if (g < 1638400) { g -= 1605632; src = wk;  dst = wkb; }
    else                  { g -= 1638400; src = wv;  dst = wvb; }
    const float4 f0 = *reinterpret_cast<const float4*>(src + (size_t)g * 8);
    const float4 f1 = *reinterpret_cast<const float4*>(src + (size_t)g * 8 + 4);
    bf16x8 v;
    v[0]=(bf16)f0.x; v[1]=(bf16)f0.y; v[2]=(bf16)f0.z; v[3]=(bf16)f0.w;
    v[4]=(bf16)f1.x; v[5]=(bf16)f1.y; v[6]=(bf16)f1.z; v[7]=(bf16)f1.w;
    *reinterpret_cast<bf16x8*>(dst + (size_t)g * 8) = v;
}

// ---------------- Projection GEMMs (bf16 in): out = A @ W^T + b, stored bf16 ---------------
// KV=false: Q row-major. KV=true: K row-major + V transposed Vt[b][e][t].
template<bool KV>
__global__ __launch_bounds__(256) void proj_kernel(const bf16* __restrict__ A,
    const bf16* __restrict__ W0, const float* __restrict__ b0, bf16* __restrict__ out0,
    const bf16* __restrict__ W1, const float* __restrict__ b1, bf16* __restrict__ out1)
{
    __shared__ __align__(16) bf16 As[2][64][40];
    __shared__ __align__(16) bf16 W0s[2][64][40];
    __shared__ __align__(16) bf16 W1s[2][64][40];

    const int tid  = threadIdx.x;
    const int w    = tid >> 6, lane = tid & 63, quad = lane >> 4, l15 = lane & 15;
    const int wr   = w >> 1, wc = w & 1;
    const int n0   = blockIdx.x * 64;
    const int m0   = blockIdx.y * 64;
    const int srow = tid >> 2;
    const int scol = (tid & 3) * 8;

    f32x4 acc0[2][2] = {}, acc1[2][2] = {};
    bf16x8 ra, rw0, rw1;

    auto prefetch = [&](int kk) {
        ra  = *reinterpret_cast<const bf16x8*>(A  + (size_t)(m0 + srow) * DM + kk + scol);
        rw0 = *reinterpret_cast<const bf16x8*>(W0 + (size_t)(n0 + srow) * DM + kk + scol);
        if constexpr (KV)
            rw1 = *reinterpret_cast<const bf16x8*>(W1 + (size_t)(n0 + srow) * DM + kk + scol);
    };
    auto store_lds = [&](int p) {
        *reinterpret_cast<bf16x8*>(&As[p][srow][scol])  = ra;
        *reinterpret_cast<bf16x8*>(&W0s[p][srow][scol]) = rw0;
        if constexpr (KV)
            *reinterpret_cast<bf16x8*>(&W1s[p][srow][scol]) = rw1;
    };

    prefetch(0);
    store_lds(0);
    __syncthreads();

    for (int step = 0; step < 16; step++) {
        const int p = step & 1;
        if (step < 15) prefetch((step + 1) * 32);

        bf16x8 af[2], bf0[2], bf1[2];
#pragma unroll
        for (int mt = 0; mt < 2; mt++)
            af[mt] = *reinterpret_cast<const bf16x8*>(&As[p][32*wr + 16*mt + l15][quad*8]);
#pragma unroll
        for (int nt = 0; nt < 2; nt++)
            bf0[nt] = *reinterpret_cast<const bf16x8*>(&W0s[p][32*wc + 16*nt + l15][quad*8]);
        if constexpr (KV) {
#pragma unroll
            for (int nt = 0; nt < 2; nt++)
                bf1[nt] = *reinterpret_cast<const bf16x8*>(&W1s[p][32*wc + 16*nt + l15][quad*8]);
        }
#pragma unroll
        for (int mt = 0; mt < 2; mt++)
#pragma unroll
            for (int nt = 0; nt < 2; nt++) {
                acc0[mt][nt] = __builtin_amdgcn_mfma_f32_16x16x32_bf16(af[mt], bf0[nt], acc0[mt][nt], 0, 0, 0);
                if constexpr (KV)
                    acc1[mt][nt] = __builtin_amdgcn_mfma_f32_16x16x32_bf16(af[mt], bf1[nt], acc1[mt][nt], 0, 0, 0);
            }

        if (step < 15) store_lds(p ^ 1);
        __syncthreads();
    }

#pragma unroll
    for (int mt = 0; mt < 2; mt++)
#pragma unroll
        for (int nt = 0; nt < 2; nt++) {
            const int coll = 32*wc + 16*nt + l15;
            const int rowl = 32*wr + 16*mt + quad*4;
            {
                const float bv = b0[n0 + coll];
                f32x4 c = acc0[mt][nt];
#pragma unroll
                for (int r = 0; r < 4; r++)
                    out0[(size_t)(m0 + rowl + r) * DM + n0 + coll] = (bf16)(c[r] + bv);
            }
            if constexpr (KV) {
                const float bv = b1[n0 + coll];
                f32x4 c = acc1[mt][nt];
                const int gr = m0 + rowl;
                const int bidx = gr >> 12, t = gr & 4095;
                const int e = n0 + coll;
                union { uint2 u; bf16 h[4]; } pk;
#pragma unroll
                for (int r = 0; r < 4; r++) pk.h[r] = (bf16)(c[r] + bv);
                *reinterpret_cast<uint2*>(out1 + (((size_t)(bidx * 512 + e)) << 12) + t) = pk.u;
            }
        }
}

// ---------------- Fused attention: producer-consumer, BM=64, BN=64 -------------------------
// 512 threads / 8 waves, 1 block/CU (LDS 88.3KB), grid 256 = 1 residency round.
// Waves 0-3 (QK producers): wave wc computes S[64q][16 kv cols 16wc..] streaming K from
//   global (disjoint rows), exp -> Ps[buf] (double-buffered) + lsum.
// Waves 4-7 (PV consumers): wave wc computes O[64q][128 e cols 128wc..] streaming V from
//   global (disjoint cols), A = Ps[buf]. One barrier per tile; QK(t+1) overlaps PV(t).
__global__ __launch_bounds__(512, 2) void attn_kernel(const bf16* __restrict__ Qb,
                                                      const bf16* __restrict__ Kb,
                                                      const bf16* __restrict__ Vt,
                                                      float* __restrict__ Op,
                                                      float* __restrict__ lp)
{
    __shared__ __align__(16) bf16 Qs[64][528];      // 67,584 B; 264 dw stride (mod32=8)
    __shared__ __align__(16) bf16 Ps[2][64][80];    // 20,480 B; 40 dw stride
    __shared__ float lred[64];

    const int tid  = threadIdx.x;
    const int w    = tid >> 6, lane = tid & 63, quad = lane >> 4, l15 = lane & 15;
    const int wc   = w & 3;                          // role-local column group

    // XCD-swizzle: 8 (b,z) combos map 1:1 onto 8 XCDs (K/V slice 4MB ~ L2/XCD).
    const int id = blockIdx.x;                       // 256 blocks
    const int combo = id & 7, qblk = id >> 3;        // qblk 0..31
    const int b = combo & 3, z = combo >> 2;
    const int q0 = qblk * 64;
    const int KVLEN = 2048, NT = 32, tb = z * KVLEN;

    // stage Q tile [64][512] once (all 512 threads)
    {
        const bf16* src = Qb + (size_t)(b * 2048 + q0) * DM;
#pragma unroll
        for (int i = 0; i < 8; i++) {
            const int G = tid + 512 * i;             // 4096 chunks of 16 B
            const int row = G >> 6, cg = G & 63;
            *reinterpret_cast<bf16x8*>(&Qs[row][cg * 8]) =
                *reinterpret_cast<const bf16x8*>(src + (size_t)row * DM + cg * 8);
        }
    }
    if (tid < 64) lred[tid] = 0.f;
    __syncthreads();

    float lsum[4][4] = {};                           // QK waves
    f32x4 oacc[4][8] = {};                           // PV waves
    const float kexp = 1.44269504088896f * 0.044194173824159216f;  // log2(e)/sqrt(512)

    const bf16* krow0 = Kb + (size_t)(b * 4096 + tb + 16*wc + l15) * DM + quad * 8;
    const bf16* vrow0 = Vt + ((size_t)(b * 512 + 128*wc + l15) << 12) + tb + quad * 8;

    auto produce = [&](int tt) {
        f32x4 sacc[4] = {};
        const bf16* krow = krow0 + (size_t)tt * 64 * DM;
#pragma unroll 8
        for (int k4 = 0; k4 < 16; k4++) {
            bf16x8 bfr = *reinterpret_cast<const bf16x8*>(krow + k4 * 32);
#pragma unroll
            for (int mt = 0; mt < 4; mt++) {
                bf16x8 afr = *reinterpret_cast<const bf16x8*>(&Qs[16*mt + l15][k4*32 + quad*8]);
                sacc[mt] = __builtin_amdgcn_mfma_f32_16x16x32_bf16(afr, bfr, sacc[mt], 0, 0, 0);
            }
        }
        const int buf = tt & 1;
#pragma unroll
        for (int mt = 0; mt < 4; mt++)
#pragma unroll
            for (int r = 0; r < 4; r++) {
                const float p = exp2f(sacc[mt][r] * kexp);
                lsum[mt][r] += p;
                Ps[buf][16*mt + quad*4 + r][16*wc + l15] = (bf16)p;
            }
    };
    auto consume = [&](int tt) {
        const int buf = tt & 1;
        const bf16* vrow = vrow0 + tt * 64;
#pragma unroll
        for (int ks2 = 0; ks2 < 2; ks2++) {
            bf16x8 ap[4];
#pragma unroll
            for (int mt = 0; mt < 4; mt++)
                ap[mt] = *reinterpret_cast<const bf16x8*>(&Ps[buf][16*mt + l15][ks2*32 + quad*8]);
#pragma unroll
            for (int nt = 0; nt < 8; nt++) {
                bf16x8 vf = *reinterpret_cast<const bf16x8*>(vrow + ((size_t)(16*nt) << 12) + ks2*32);
#pragma unroll
                for (int mt = 0; mt < 4; mt++)
                    oacc[mt][nt] = __builtin_amdgcn_mfma_f32_16x16x32_bf16(ap[mt], vf, oacc[mt][nt], 0, 0, 0);
            }
        }
    };

    if (w < 4) produce(0);
    __syncthreads();                                  // Ps[0] ready

    for (int t = 0; t < NT; t++) {
        if (w < 4) {
            if (t + 1 < NT) produce(t + 1);           // fill Ps[(t+1)&1]
        } else {
            consume(t);                               // drain Ps[t&1]
        }
        __syncthreads();                              // buf handoff
    }

    // epilogue: l reduction (QK waves), O write (PV waves)
    if (w < 4) {
#pragma unroll
        for (int mt = 0; mt < 4; mt++)
#pragma unroll
            for (int r = 0; r < 4; r++)
                atomicAdd(&lred[16*mt + quad*4 + r], lsum[mt][r]);
    }
    __syncthreads();

    if (tid < 64) lp[(size_t)z * 8192 + b * 2048 + q0 + tid] = lred[tid];
    if (w >= 4) {
#pragma unroll
        for (int mt = 0; mt < 4; mt++)
#pragma unroll
            for (int r = 0; r < 4; r++) {
                const int row = 16*mt + quad*4 + r;
                float* obase = Op + ((size_t)z * 8192 + b * 2048 + q0 + row) * DM;
#pragma unroll
                for (int nt = 0; nt < 8; nt++)
                    obase[128*wc + 16*nt + l15] = oacc[mt][nt][r];
            }
    }
}

// ---------------- Combine split partials: out = sum_z Op[z] / sum_z l[z] -------------------
__global__ __launch_bounds__(256) void reduce_kernel(const float* __restrict__ Op,
                                                     const float* __restrict__ lp,
                                                     float* __restrict__ out)
{
    const int g = blockIdx.x * 256 + threadIdx.x;    // 1,048,576 threads x float4
    const size_t e = (size_t)g * 4;
    const int row = g >> 7;
    float4 o = *reinterpret_cast<const float4*>(Op + e);
    float4 a = *reinterpret_cast<const float4*>(Op + 4194304 + e);
    const float l = lp[row] + lp[8192 + row];
    const float linv = 1.0f / l;
    o.x = (o.x + a.x) * linv;
    o.y = (o.y + a.y) * linv;
    o.z = (o.z + a.z) * linv;
    o.w = (o.w + a.w) * linv;
    *reinterpret_cast<float4*>(out + e) = o;
}

extern "C" void kernel_launch(void* const* d_in, const int* in_sizes, int n_in,
                              void* d_out, int out_size, void* d_ws, size_t ws_size,
                              hipStream_t stream)
{
    const float* x   = (const float*)d_in[0];
    const float* enc = (const float*)d_in[1];
    const float* wq  = (const float*)d_in[2];
    const float* bq  = (const float*)d_in[3];
    const float* wk  = (const float*)d_in[4];
    const float* bk  = (const float*)d_in[5];
    const float* wv  = (const float*)d_in[6];
    const float* bv  = (const float*)d_in[7];
    float* out = (float*)d_out;

    char* ws = (char*)d_ws;
    bf16*  Qb   = (bf16*)ws;
    bf16*  Kb   = (bf16*)(ws + 8388608);
    bf16*  Vt   = (bf16*)(ws + 25165824);
    bf16*  xb   = (bf16*)(ws + 41943040);
    bf16*  encb = (bf16*)(ws + 50331648);
    bf16*  wqb  = (bf16*)(ws + 67108864);
    bf16*  wkb  = (bf16*)(ws + 67633152);
    bf16*  wvb  = (bf16*)(ws + 68157440);
    float* Op   = (float*)(ws + 41943040);          // overlaps xb/encb/w*b (phase 2)
    float* lp   = (float*)(ws + 41943040 + 2ull * 16777216);

    // prepass: fp32 -> bf16, single launch
    hipLaunchKernelGGL(cvt_all_kernel, dim3(6528), dim3(256), 0, stream,
                       x, xb, enc, encb, wq, wqb, wk, wkb, wv, wvb);

    // projections
    hipLaunchKernelGGL((proj_kernel<false>), dim3(8, 128), dim3(256), 0, stream,
                       xb, wqb, bq, Qb, (const bf16*)nullptr, (const float*)nullptr, (bf16*)nullptr);
    hipLaunchKernelGGL((proj_kernel<true>),  dim3(8, 256), dim3(256), 0, stream,
                       encb, wkb, bk, Kb, wvb, bv, Vt);

    // attention (NSPLIT=2, 256 blocks x 512 threads, 1 block/CU) + combine
    hipLaunchKernelGGL(attn_kernel, dim3(256), dim3(512), 0, stream, Qb, Kb, Vt, Op, lp);
    hipLaunchKernelGGL(reduce_kernel, dim3(4096), dim3(256), 0, stream, Op, lp, out);
}

// Round 4
// 270.149 us; speedup vs baseline: 1.5359x; 1.1668x over previous
//
#include <hip/hip_runtime.h>
#include <hip/hip_bf16.h>

// DecoderLayer cross-attention, MI355X/gfx950. Round 7.
// B=4, Sq=2048, Skv=4096, D=512. fp32 in/out, bf16 MFMA internally.
// R7 thesis (from R3-R6 dataset): duration tracks VMEM segment traffic; all K/V loads
// were 16-segment scatters. Fix = contiguous 1KB bursts everywhere:
//  - Q A-frags in registers (af[16], loaded once) -> Qs LDS eliminated.
//  - K staged to LDS via global_load_lds (1 contiguous row/instr), double-buffered,
//    XOR-swizzled via pre-swizzled SOURCE lane (linear dest, swz on read; m214 recipe).
//  - V re-tiled in ws as Vtg[b][t/32][e][t%32] so PV B-frags load 1KB contiguous into
//    registers at tile start (T14: QK covers the latency).
//  - 8 waves lockstep, KT=64, 2 syncthreads/tile, NT=32, LDS 141.6KB, 1 block/CU,
//    grid 256 = one residency round, NSPLIT=2.
// ws layout:
//   Qb  bf16 [8192][512]          @ 0           (8,388,608)
//   Kb  bf16 [16384][512]         @ 8,388,608   (16,777,216)
//   Vtg bf16 [4][128][512][32]    @ 25,165,824  (16,777,216)   (t-tiled!)
//   region B @ 41,943,040:
//     phase1: xb 8.4M | encb @+8.4M 16.8M | wqb/wkb/wvb @+25.2M 0.5M each
//     phase2: Op f32 [2][8192][512] | lp f32 [2][8192]  (need 75,563,008 B)

typedef __bf16 bf16;
typedef __attribute__((ext_vector_type(8))) __bf16 bf16x8;
typedef __attribute__((ext_vector_type(4))) float f32x4;

#define DM 512

__device__ __forceinline__ void gload_lds16(const bf16* g, bf16* l)
{
    __builtin_amdgcn_global_load_lds(
        (const __attribute__((address_space(1))) void*)g,
        (__attribute__((address_space(3))) void*)l, 16, 0, 0);
}

// ---------------- fp32 -> bf16 convert prepass (single launch, 5 regions) -----------------
__global__ __launch_bounds__(256) void cvt_all_kernel(
    const float* __restrict__ x,   bf16* __restrict__ xb,
    const float* __restrict__ enc, bf16* __restrict__ encb,
    const float* __restrict__ wq,  bf16* __restrict__ wqb,
    const float* __restrict__ wk,  bf16* __restrict__ wkb,
    const float* __restrict__ wv,  bf16* __restrict__ wvb)
{
    int g = blockIdx.x * 256 + threadIdx.x;
    const float* src; bf16* dst;
    if (g < 524288)       { src = x;   dst = xb; }
    else if (g < 1572864) { g -= 524288;  src = enc; dst = encb; }
    else if (g < 1605632) { g -= 1572864; src = wq;  dst = wqb; }
    else if (g < 1638400) { g -= 1605632; src = wk;  dst = wkb; }
    else                  { g -= 1638400; src = wv;  dst = wvb; }
    const float4 f0 = *reinterpret_cast<const float4*>(src + (size_t)g * 8);
    const float4 f1 = *reinterpret_cast<const float4*>(src + (size_t)g * 8 + 4);
    bf16x8 v;
    v[0]=(bf16)f0.x; v[1]=(bf16)f0.y; v[2]=(bf16)f0.z; v[3]=(bf16)f0.w;
    v[4]=(bf16)f1.x; v[5]=(bf16)f1.y; v[6]=(bf16)f1.z; v[7]=(bf16)f1.w;
    *reinterpret_cast<bf16x8*>(dst + (size_t)g * 8) = v;
}

// ---------------- Projection GEMMs (bf16 in): out = A @ W^T + b, stored bf16 ---------------
// KV=false: Q row-major. KV=true: K row-major + V t-tiled Vtg[b][t>>5][e][t&31].
template<bool KV>
__global__ __launch_bounds__(256) void proj_kernel(const bf16* __restrict__ A,
    const bf16* __restrict__ W0, const float* __restrict__ b0, bf16* __restrict__ out0,
    const bf16* __restrict__ W1, const float* __restrict__ b1, bf16* __restrict__ out1)
{
    __shared__ __align__(16) bf16 As[2][64][40];
    __shared__ __align__(16) bf16 W0s[2][64][40];
    __shared__ __align__(16) bf16 W1s[2][64][40];

    const int tid  = threadIdx.x;
    const int w    = tid >> 6, lane = tid & 63, quad = lane >> 4, l15 = lane & 15;
    const int wr   = w >> 1, wc = w & 1;
    const int n0   = blockIdx.x * 64;
    const int m0   = blockIdx.y * 64;
    const int srow = tid >> 2;
    const int scol = (tid & 3) * 8;

    f32x4 acc0[2][2] = {}, acc1[2][2] = {};
    bf16x8 ra, rw0, rw1;

    auto prefetch = [&](int kk) {
        ra  = *reinterpret_cast<const bf16x8*>(A  + (size_t)(m0 + srow) * DM + kk + scol);
        rw0 = *reinterpret_cast<const bf16x8*>(W0 + (size_t)(n0 + srow) * DM + kk + scol);
        if constexpr (KV)
            rw1 = *reinterpret_cast<const bf16x8*>(W1 + (size_t)(n0 + srow) * DM + kk + scol);
    };
    auto store_lds = [&](int p) {
        *reinterpret_cast<bf16x8*>(&As[p][srow][scol])  = ra;
        *reinterpret_cast<bf16x8*>(&W0s[p][srow][scol]) = rw0;
        if constexpr (KV)
            *reinterpret_cast<bf16x8*>(&W1s[p][srow][scol]) = rw1;
    };

    prefetch(0);
    store_lds(0);
    __syncthreads();

    for (int step = 0; step < 16; step++) {
        const int p = step & 1;
        if (step < 15) prefetch((step + 1) * 32);

        bf16x8 af[2], bf0[2], bf1[2];
#pragma unroll
        for (int mt = 0; mt < 2; mt++)
            af[mt] = *reinterpret_cast<const bf16x8*>(&As[p][32*wr + 16*mt + l15][quad*8]);
#pragma unroll
        for (int nt = 0; nt < 2; nt++)
            bf0[nt] = *reinterpret_cast<const bf16x8*>(&W0s[p][32*wc + 16*nt + l15][quad*8]);
        if constexpr (KV) {
#pragma unroll
            for (int nt = 0; nt < 2; nt++)
                bf1[nt] = *reinterpret_cast<const bf16x8*>(&W1s[p][32*wc + 16*nt + l15][quad*8]);
        }
#pragma unroll
        for (int mt = 0; mt < 2; mt++)
#pragma unroll
            for (int nt = 0; nt < 2; nt++) {
                acc0[mt][nt] = __builtin_amdgcn_mfma_f32_16x16x32_bf16(af[mt], bf0[nt], acc0[mt][nt], 0, 0, 0);
                if constexpr (KV)
                    acc1[mt][nt] = __builtin_amdgcn_mfma_f32_16x16x32_bf16(af[mt], bf1[nt], acc1[mt][nt], 0, 0, 0);
            }

        if (step < 15) store_lds(p ^ 1);
        __syncthreads();
    }

#pragma unroll
    for (int mt = 0; mt < 2; mt++)
#pragma unroll
        for (int nt = 0; nt < 2; nt++) {
            const int coll = 32*wc + 16*nt + l15;
            const int rowl = 32*wr + 16*mt + quad*4;
            {
                const float bv = b0[n0 + coll];
                f32x4 c = acc0[mt][nt];
#pragma unroll
                for (int r = 0; r < 4; r++)
                    out0[(size_t)(m0 + rowl + r) * DM + n0 + coll] = (bf16)(c[r] + bv);
            }
            if constexpr (KV) {
                const float bv = b1[n0 + coll];
                f32x4 c = acc1[mt][nt];
                const int gr = m0 + rowl;
                const int bidx = gr >> 12, t = gr & 4095;
                const int e = n0 + coll;
                union { uint2 u; bf16 h[4]; } pk;
#pragma unroll
                for (int r = 0; r < 4; r++) pk.h[r] = (bf16)(c[r] + bv);
                // t-tiled: Vtg[bidx][t>>5][e][t&31], t % 4 == 0 -> 4 contiguous elems
                *reinterpret_cast<uint2*>(out1 +
                    ((((size_t)(bidx*128 + (t >> 5)) * DM + e) << 5) + (t & 31))) = pk.u;
            }
        }
}

// ---------------- Fused attention: contiguous-burst, LDS-K, reg-Q/V --------------------------
// 512 threads / 8 waves, 1 block/CU, grid 256 = 1 round.
// QK: wave (qb=w>>1, cb0=2*(w&1)): S[16qb..+16][16cb0..+32]; A = Q regs, B = Kt LDS (swz).
// PV: wave w: O[64 q][64 e cols 64w..]; A = Ps LDS, B = V regs (t-tiled contiguous loads).
__global__ __launch_bounds__(512, 2) void attn_kernel(const bf16* __restrict__ Qb,
                                                      const bf16* __restrict__ Kb,
                                                      const bf16* __restrict__ Vtg,
                                                      float* __restrict__ Op,
                                                      float* __restrict__ lp)
{
    __shared__ __align__(16) bf16 Kt[2][64][512];   // 131,072 B; rows XOR-swizzled (src-side)
    __shared__ __align__(16) bf16 Ps[64][80];       //  10,240 B; 40 dw stride (mod32=8, proven)
    __shared__ float lred[64];

    const int tid  = threadIdx.x;
    const int w    = tid >> 6, lane = tid & 63, quad = lane >> 4, l15 = lane & 15;
    const int qb   = w >> 1;                 // QK q-row block 0..3
    const int cb0  = (w & 1) * 2;            // QK kv col blocks {cb0, cb0+1}

    // XCD-swizzle: 8 (b,z) combos map 1:1 onto 8 XCDs.
    const int id = blockIdx.x;               // 256 blocks
    const int combo = id & 7, qblk = id >> 3;
    const int b = combo & 3, z = combo >> 2;
    const int q0 = qblk * 64;
    const int NT = 32, tb = z * 2048;        // 32 tiles of 64 kv rows

    // ---- Q A-fragments into registers (once; replaces Qs LDS + per-tile re-reads) ----
    bf16x8 af[16];
    {
        const bf16* qsrc = Qb + (size_t)(b*2048 + q0 + 16*qb + l15) * DM + quad*8;
#pragma unroll
        for (int k4 = 0; k4 < 16; k4++) af[k4] = *reinterpret_cast<const bf16x8*>(qsrc + k4*32);
    }
    if (tid < 64) lred[tid] = 0.f;

    const bf16* kbase = Kb + (size_t)(b*4096 + tb) * DM;
    // ---- stage K tile 0 (each instr: 1 contiguous 1KB row; source lane pre-swizzled) ----
#pragma unroll
    for (int i = 0; i < 8; i++) {
        const int row = w + 8*i;             // row & 7 == w
        gload_lds16(kbase + (size_t)row * DM + ((lane ^ w) * 8), &Kt[0][row][0]);
    }
    __syncthreads();                          // drains DMA (vmcnt0), publishes lred

    f32x4 oacc[4][4] = {};
    float lsum[2][4] = {};
    const float kexp = 1.44269504088896f * 0.044194173824159216f;  // log2(e)/sqrt(512)
    const int sxor = (l15 & 7) << 4;          // read-side XOR for Kt rows (row&7 == l15&7)

    for (int t = 0; t < NT; t++) {
        const int buf = t & 1;

        // prefetch next K tile into other buffer (latency hidden by this tile's compute)
        if (t + 1 < NT) {
            const bf16* ksrc = kbase + (size_t)(t + 1) * 64 * DM;
#pragma unroll
            for (int i = 0; i < 8; i++) {
                const int row = w + 8*i;
                gload_lds16(ksrc + (size_t)row * DM + ((lane ^ w) * 8), &Kt[buf ^ 1][row][0]);
            }
        }

        // V fragments for THIS tile: contiguous 1KB bursts from t-tiled layout (T14)
        bf16x8 vf[4][2];
#pragma unroll
        for (int ks = 0; ks < 2; ks++) {
            const size_t tblk = (size_t)(b*128 + z*64 + t*2 + ks) * DM;
#pragma unroll
            for (int nt = 0; nt < 4; nt++)
                vf[nt][ks] = *reinterpret_cast<const bf16x8*>(
                    Vtg + ((tblk + 64*w + 16*nt + l15) << 5) + quad*8);
        }

        // ---- QK: S[16qb..+16][16(cb0..cb0+2)] , A regs x B LDS ----
        f32x4 sacc[2] = {};
        const char* krowA = (const char*)&Kt[buf][16*cb0 + l15][0];
        const char* krowB = (const char*)&Kt[buf][16*cb0 + 16 + l15][0];
#pragma unroll
        for (int k4 = 0; k4 < 16; k4++) {
            const int off = (k4*64 + quad*16) ^ sxor;
            bf16x8 k0 = *reinterpret_cast<const bf16x8*>(krowA + off);
            bf16x8 k1 = *reinterpret_cast<const bf16x8*>(krowB + off);
            sacc[0] = __builtin_amdgcn_mfma_f32_16x16x32_bf16(af[k4], k0, sacc[0], 0, 0, 0);
            sacc[1] = __builtin_amdgcn_mfma_f32_16x16x32_bf16(af[k4], k1, sacc[1], 0, 0, 0);
        }

        // exp -> Ps (C-layout -> A-layout), accumulate l
#pragma unroll
        for (int s = 0; s < 2; s++)
#pragma unroll
            for (int r = 0; r < 4; r++) {
                const float p = exp2f(sacc[s][r] * kexp);
                lsum[s][r] += p;
                Ps[16*qb + quad*4 + r][16*(cb0 + s) + l15] = (bf16)p;
            }
        __syncthreads();                      // Ps ready (also drains prefetch+vf)

        // ---- PV: O[64][64w..+64] += P[64][64] * V[64][...] , A LDS x B regs ----
#pragma unroll
        for (int ks = 0; ks < 2; ks++) {
            bf16x8 ap[4];
#pragma unroll
            for (int mt = 0; mt < 4; mt++)
                ap[mt] = *reinterpret_cast<const bf16x8*>(&Ps[16*mt + l15][ks*32 + quad*8]);
#pragma unroll
            for (int nt = 0; nt < 4; nt++)
#pragma unroll
                for (int mt = 0; mt < 4; mt++)
                    oacc[mt][nt] = __builtin_amdgcn_mfma_f32_16x16x32_bf16(ap[mt], vf[nt][ks], oacc[mt][nt], 0, 0, 0);
        }
        __syncthreads();                      // protect Ps + Kt[buf] for next tile
    }

    // ---- epilogue: l reduction + O partial write ----
#pragma unroll
    for (int r = 0; r < 4; r++)
        atomicAdd(&lred[16*qb + quad*4 + r], lsum[0][r] + lsum[1][r]);
    __syncthreads();

    if (tid < 64) lp[(size_t)z * 8192 + b * 2048 + q0 + tid] = lred[tid];
#pragma unroll
    for (int mt = 0; mt < 4; mt++)
#pragma unroll
        for (int r = 0; r < 4; r++) {
            const int row = 16*mt + quad*4 + r;
            float* obase = Op + ((size_t)z * 8192 + b * 2048 + q0 + row) * DM;
#pragma unroll
            for (int nt = 0; nt < 4; nt++)
                obase[64*w + 16*nt + l15] = oacc[mt][nt][r];
        }
}

// ---------------- Combine split partials: out = sum_z Op[z] / sum_z l[z] -------------------
__global__ __launch_bounds__(256) void reduce_kernel(const float* __restrict__ Op,
                                                     const float* __restrict__ lp,
                                                     float* __restrict__ out)
{
    const int g = blockIdx.x * 256 + threadIdx.x;    // 1,048,576 threads x float4
    const size_t e = (size_t)g * 4;
    const int row = g >> 7;
    float4 o = *reinterpret_cast<const float4*>(Op + e);
    float4 a = *reinterpret_cast<const float4*>(Op + 4194304 + e);
    const float l = lp[row] + lp[8192 + row];
    const float linv = 1.0f / l;
    o.x = (o.x + a.x) * linv;
    o.y = (o.y + a.y) * linv;
    o.z = (o.z + a.z) * linv;
    o.w = (o.w + a.w) * linv;
    *reinterpret_cast<float4*>(out + e) = o;
}

extern "C" void kernel_launch(void* const* d_in, const int* in_sizes, int n_in,
                              void* d_out, int out_size, void* d_ws, size_t ws_size,
                              hipStream_t stream)
{
    const float* x   = (const float*)d_in[0];
    const float* enc = (const float*)d_in[1];
    const float* wq  = (const float*)d_in[2];
    const float* bq  = (const float*)d_in[3];
    const float* wk  = (const float*)d_in[4];
    const float* bk  = (const float*)d_in[5];
    const float* wv  = (const float*)d_in[6];
    const float* bv  = (const float*)d_in[7];
    float* out = (float*)d_out;

    char* ws = (char*)d_ws;
    bf16*  Qb   = (bf16*)ws;
    bf16*  Kb   = (bf16*)(ws + 8388608);
    bf16*  Vtg  = (bf16*)(ws + 25165824);
    bf16*  xb   = (bf16*)(ws + 41943040);
    bf16*  encb = (bf16*)(ws + 50331648);
    bf16*  wqb  = (bf16*)(ws + 67108864);
    bf16*  wkb  = (bf16*)(ws + 67633152);
    bf16*  wvb  = (bf16*)(ws + 68157440);
    float* Op   = (float*)(ws + 41943040);          // overlaps xb/encb/w*b (phase 2)
    float* lp   = (float*)(ws + 41943040 + 2ull * 16777216);

    // prepass: fp32 -> bf16, single launch
    hipLaunchKernelGGL(cvt_all_kernel, dim3(6528), dim3(256), 0, stream,
                       x, xb, enc, encb, wq, wqb, wk, wkb, wv, wvb);

    // projections
    hipLaunchKernelGGL((proj_kernel<false>), dim3(8, 128), dim3(256), 0, stream,
                       xb, wqb, bq, Qb, (const bf16*)nullptr, (const float*)nullptr, (bf16*)nullptr);
    hipLaunchKernelGGL((proj_kernel<true>),  dim3(8, 256), dim3(256), 0, stream,
                       encb, wkb, bk, Kb, wvb, bv, Vtg);

    // attention (256 blocks x 512 threads, 1 block/CU) + combine
    hipLaunchKernelGGL(attn_kernel, dim3(256), dim3(512), 0, stream, Qb, Kb, Vtg, Op, lp);
    hipLaunchKernelGGL(reduce_kernel, dim3(4096), dim3(256), 0, stream, Op, lp, out);
}